// Round 3
// baseline (462.122 us; speedup 1.0000x reference)
//
#include <hip/hip_runtime.h>
#include <hip/hip_bf16.h>
#include <math.h>

typedef __bf16 bf16_t;
typedef bf16_t bf16x8 __attribute__((ext_vector_type(8)));
typedef float  f32x4  __attribute__((ext_vector_type(4)));

#define SEQ 200
#define DD  64
#define RS2 72   // h-tile LDS row stride (144 B)

#define MFMA(a, b, c) __builtin_amdgcn_mfma_f32_16x16x32_bf16((a), (b), (c), 0, 0, 0)
#define LGKM0() asm volatile("s_waitcnt lgkmcnt(0)" ::: "memory")

// ---------------- prep kernel (1 block): weight transforms only ----------------
__global__ __launch_bounds__(256) void prep_kernel(
    const float* __restrict__ W1, const float* __restrict__ W2,
    bf16_t* __restrict__ Wbc, bf16_t* __restrict__ W1dt,
    bf16_t* __restrict__ W2t, float* __restrict__ W1sT)
{
  const int tid = threadIdx.x;
  for (int i = tid; i < 64 * 64; i += 256) {
    int n = i >> 6, k = i & 63;
    Wbc[i]  = (bf16_t)(W1[(64 + k) * 64 + n] - W1[(128 + k) * 64 + n]);
    W1dt[i] = (bf16_t)(W1[(192 + k) * 64 + n]);
    W1sT[i] = W1[k * 64 + n] + W1[(128 + k) * 64 + n];   // fp32, exact Q
  }
  for (int i = tid; i < 32 * 64; i += 256) {
    int n = i >> 6, k = i & 63;
    W2t[i] = (bf16_t)(W2[k * 32 + n]);
  }
}

// tile load into NAMED float4 registers (no pointer-indirected buffers -> no scratch)
#define LOADT(t, Y0, Y1, Y2, Y3) do {                                          \
    if ((t) == 12 && l16 >= 8) {                                               \
      Y0 = Y1 = Y2 = Y3 = make_float4(0.f, 0.f, 0.f, 0.f);                     \
    } else {                                                                   \
      const float4* p_ = Xr + ((16 * (t) + l16) * 16 + 2 * g);                 \
      Y0 = p_[0]; Y1 = p_[1]; Y2 = p_[8]; Y3 = p_[9];                          \
    }                                                                          \
  } while (0)

// full per-tile fused pipeline: stage1 MFMA -> LDS transpose -> stage2 MFMA ->
// stage3 dot -> logit broadcast (shuffle, no LDS) -> online softmax + pooling
#define PROCBODY(t, Y0, Y1, Y2, Y3) do {                                       \
    bf16x8 a0_, a1_;                                                           \
    a0_[0]=(bf16_t)Y0.x; a0_[1]=(bf16_t)Y0.y; a0_[2]=(bf16_t)Y0.z; a0_[3]=(bf16_t)Y0.w; \
    a0_[4]=(bf16_t)Y1.x; a0_[5]=(bf16_t)Y1.y; a0_[6]=(bf16_t)Y1.z; a0_[7]=(bf16_t)Y1.w; \
    a1_[0]=(bf16_t)Y2.x; a1_[1]=(bf16_t)Y2.y; a1_[2]=(bf16_t)Y2.z; a1_[3]=(bf16_t)Y2.w; \
    a1_[4]=(bf16_t)Y3.x; a1_[5]=(bf16_t)Y3.y; a1_[6]=(bf16_t)Y3.z; a1_[7]=(bf16_t)Y3.w; \
    f32x4 c0_ = {0.f,0.f,0.f,0.f}, c1_ = c0_, c2_ = c0_, c3_ = c0_;            \
    c0_ = MFMA(a0_, bB[0][0], c0_); c0_ = MFMA(a1_, bB[0][1], c0_);            \
    c1_ = MFMA(a0_, bB[1][0], c1_); c1_ = MFMA(a1_, bB[1][1], c1_);            \
    c2_ = MFMA(a0_, bB[2][0], c2_); c2_ = MFMA(a1_, bB[2][1], c2_);            \
    c3_ = MFMA(a0_, bB[3][0], c3_); c3_ = MFMA(a1_, bB[3][1], c3_);            \
    _Pragma("unroll")                                                          \
    for (int r_ = 0; r_ < 4; ++r_) {                                           \
      int rowb_ = (4 * g + r_) * RS2 + l16;                                    \
      hw[rowb_]      = (bf16_t)fmaxf(c0_[r_] + qn0, 0.f);                      \
      hw[rowb_ + 16] = (bf16_t)fmaxf(c1_[r_] + qn1, 0.f);                      \
      hw[rowb_ + 32] = (bf16_t)fmaxf(c2_[r_] + qn2, 0.f);                      \
      hw[rowb_ + 48] = (bf16_t)fmaxf(c3_[r_] + qn3, 0.f);                      \
    }                                                                          \
    LGKM0();                                                                   \
    bf16x8 h0_ = *(const bf16x8*)&hw[l16 * RS2 + 8 * g];                       \
    bf16x8 h1_ = *(const bf16x8*)&hw[l16 * RS2 + 32 + 8 * g];                  \
    f32x4 d0_ = {0.f,0.f,0.f,0.f}, d1_ = d0_;                                  \
    d0_ = MFMA(h0_, W2f[0][0], d0_); d0_ = MFMA(h1_, W2f[1][0], d0_);          \
    d1_ = MFMA(h0_, W2f[0][1], d1_); d1_ = MFMA(h1_, W2f[1][1], d1_);          \
    float pr0_ = fmaxf(d0_[0] + b2v0, 0.f) * w3v0 + fmaxf(d1_[0] + b2v1, 0.f) * w3v1; \
    float pr1_ = fmaxf(d0_[1] + b2v0, 0.f) * w3v0 + fmaxf(d1_[1] + b2v1, 0.f) * w3v1; \
    float pr2_ = fmaxf(d0_[2] + b2v0, 0.f) * w3v0 + fmaxf(d1_[2] + b2v1, 0.f) * w3v1; \
    float pr3_ = fmaxf(d0_[3] + b2v0, 0.f) * w3v0 + fmaxf(d1_[3] + b2v1, 0.f) * w3v1; \
    _Pragma("unroll")                                                          \
    for (int o_ = 1; o_ < 16; o_ <<= 1) {                                      \
      pr0_ += __shfl_xor(pr0_, o_); pr1_ += __shfl_xor(pr1_, o_);              \
      pr2_ += __shfl_xor(pr2_, o_); pr3_ += __shfl_xor(pr3_, o_);              \
    }                                                                          \
    int s3_ = l16 & 3;                                                         \
    float pv_ = pr0_;                                                          \
    pv_ = (s3_ == 1) ? pr1_ : pv_;                                             \
    pv_ = (s3_ == 2) ? pr2_ : pv_;                                             \
    pv_ = (s3_ == 3) ? pr3_ : pv_;                                             \
    float lv_ = __shfl(pv_, ((l16 >> 2) << 4) | s3_) + b3s;                    \
    if (16 * (t) + l16 >= SEQ) lv_ = -INFINITY;                                \
    float tm_ = lv_;                                                           \
    _Pragma("unroll")                                                          \
    for (int o_ = 1; o_ < 16; o_ <<= 1) tm_ = fmaxf(tm_, __shfl_xor(tm_, o_)); \
    float mn_ = fmaxf(m, tm_);                                                 \
    float al_ = __expf(m - mn_);                                               \
    float ee_ = __expf(lv_ - mn_);                                             \
    float S_ = ee_;                                                            \
    _Pragma("unroll")                                                          \
    for (int o_ = 1; o_ < 16; o_ <<= 1) S_ += __shfl_xor(S_, o_);              \
    Z = Z * al_ + S_;                                                          \
    _Pragma("unroll")                                                          \
    for (int e_ = 0; e_ < 8; ++e_) {                                           \
      P[e_]     = P[e_]     * al_ + ee_ * (float)a0_[e_];                      \
      P[8 + e_] = P[8 + e_] * al_ + ee_ * (float)a1_[e_];                      \
    }                                                                          \
    m = mn_;                                                                   \
  } while (0)

// ---------------- main kernel: ONE WAVE per batch row, no __syncthreads ----------------
__global__ __launch_bounds__(256, 3) void din_kernel(
    const float* __restrict__ em, const float* __restrict__ eu,
    const float* __restrict__ Xu, const float* __restrict__ b1,
    const float* __restrict__ b2, const float* __restrict__ W3,
    const float* __restrict__ b3, const float* __restrict__ gam,
    const float* __restrict__ bet, const float* __restrict__ mmean,
    const float* __restrict__ mvar, const bf16_t* __restrict__ Wbc,
    const bf16_t* __restrict__ W1dt, const bf16_t* __restrict__ W2t,
    const float* __restrict__ W1sT, float* __restrict__ out, int Btot)
{
  __shared__ __align__(16) bf16_t hbuf[4][16 * RS2];   // 9216 B total

  const int tid  = threadIdx.x;
  const int lane = tid & 63;
  const int wid  = tid >> 6;
  const int g    = lane >> 4;
  const int l16  = lane & 15;
  const int b    = blockIdx.x * 4 + wid;
  if (b >= Btot) return;   // wave-uniform; kernel has no barriers

  bf16_t* hw = hbuf[wid];

  // ---- em row + slices ----
  const float* emr = em + (size_t)b * DD;
  const float em_l = emr[lane];
  float4 ef0 = *(const float4*)&emr[8 * g];
  float4 ef1 = *(const float4*)&emr[8 * g + 4];
  float4 ef2 = *(const float4*)&emr[32 + 8 * g];
  float4 ef3 = *(const float4*)&emr[32 + 8 * g + 4];

  // ---- B-fragments: stage-1 folded weights (Wbc + em_k * W1dt), 4 n-tiles ----
  const bf16x8* Wbc8  = (const bf16x8*)Wbc;
  const bf16x8* W1dt8 = (const bf16x8*)W1dt;
  const bf16x8* W2t8  = (const bf16x8*)W2t;
  bf16x8 bB[4][2];
  #pragma unroll
  for (int j = 0; j < 4; ++j) {
    #pragma unroll
    for (int c = 0; c < 2; ++c) {
      bf16x8 wbc = Wbc8[(16 * j + l16) * 8 + 4 * c + g];
      bf16x8 w1d = W1dt8[(16 * j + l16) * 8 + 4 * c + g];
      float4 e0 = c ? ef2 : ef0;
      float4 e1 = c ? ef3 : ef1;
      bf16x8 r;
      r[0] = (bf16_t)((float)wbc[0] + e0.x * (float)w1d[0]);
      r[1] = (bf16_t)((float)wbc[1] + e0.y * (float)w1d[1]);
      r[2] = (bf16_t)((float)wbc[2] + e0.z * (float)w1d[2]);
      r[3] = (bf16_t)((float)wbc[3] + e0.w * (float)w1d[3]);
      r[4] = (bf16_t)((float)wbc[4] + e1.x * (float)w1d[4]);
      r[5] = (bf16_t)((float)wbc[5] + e1.y * (float)w1d[5]);
      r[6] = (bf16_t)((float)wbc[6] + e1.z * (float)w1d[6]);
      r[7] = (bf16_t)((float)wbc[7] + e1.w * (float)w1d[7]);
      bB[j][c] = r;
    }
  }

  bf16x8 W2f[2][2];
  #pragma unroll
  for (int c = 0; c < 2; ++c)
    #pragma unroll
    for (int u = 0; u < 2; ++u)
      W2f[c][u] = W2t8[(16 * u + l16) * 8 + 4 * c + g];

  const float b2v0 = b2[l16], b2v1 = b2[16 + l16];
  const float w3v0 = W3[l16], w3v1 = W3[16 + l16];
  const float b3s  = b3[0];

  // ---- Q per row (exact fp32), em broadcast through the (not-yet-used) h buffer ----
  float* ew = (float*)hw;
  ew[lane] = em_l;
  LGKM0();
  float q = b1[lane];
  const float4* wq = (const float4*)(W1sT + lane * 64);
  #pragma unroll
  for (int dd = 0; dd < 16; ++dd) {
    float4 wv = wq[dd];
    float4 ev = *(const float4*)&ew[4 * dd];
    q += ev.x * wv.x + ev.y * wv.y + ev.z * wv.z + ev.w * wv.w;
  }
  const float qn0 = __shfl(q, l16);
  const float qn1 = __shfl(q, 16 + l16);
  const float qn2 = __shfl(q, 32 + l16);
  const float qn3 = __shfl(q, 48 + l16);

  // ---- online-softmax state ----
  float m = -INFINITY, Z = 0.f;
  float P[16];
  #pragma unroll
  for (int e = 0; e < 16; ++e) P[e] = 0.f;

  const float4* Xr = (const float4*)(Xu + (size_t)b * SEQ * DD);

  // ---- 13-tile pipeline, depth-1 prefetch, all-named registers ----
  float4 A0, A1, A2, A3, B0, B1, B2, B3;
  LOADT(0, A0, A1, A2, A3);
  LOADT(1, B0, B1, B2, B3);   PROCBODY(0,  A0, A1, A2, A3);
  LOADT(2, A0, A1, A2, A3);   PROCBODY(1,  B0, B1, B2, B3);
  LOADT(3, B0, B1, B2, B3);   PROCBODY(2,  A0, A1, A2, A3);
  LOADT(4, A0, A1, A2, A3);   PROCBODY(3,  B0, B1, B2, B3);
  LOADT(5, B0, B1, B2, B3);   PROCBODY(4,  A0, A1, A2, A3);
  LOADT(6, A0, A1, A2, A3);   PROCBODY(5,  B0, B1, B2, B3);
  LOADT(7, B0, B1, B2, B3);   PROCBODY(6,  A0, A1, A2, A3);
  LOADT(8, A0, A1, A2, A3);   PROCBODY(7,  B0, B1, B2, B3);
  LOADT(9, B0, B1, B2, B3);   PROCBODY(8,  A0, A1, A2, A3);
  LOADT(10, A0, A1, A2, A3);  PROCBODY(9,  B0, B1, B2, B3);
  LOADT(11, B0, B1, B2, B3);  PROCBODY(10, A0, A1, A2, A3);
  LOADT(12, A0, A1, A2, A3);  PROCBODY(11, B0, B1, B2, B3);
  PROCBODY(12, A0, A1, A2, A3);

  // ---- finalize pooling: reduce P over the 16 row-classes, scale by 1/Z ----
  const float invZ = 1.f / Z;
  #pragma unroll
  for (int o = 1; o < 16; o <<= 1)
    #pragma unroll
    for (int e = 0; e < 16; ++e) P[e] += __shfl_xor(P[e], o);
  float* pw = (float*)hw;
  if (l16 == 0) {
    #pragma unroll
    for (int e = 0; e < 8; ++e) {
      pw[8 * g + e]      = P[e]     * invZ;
      pw[32 + 8 * g + e] = P[8 + e] * invZ;
    }
  }
  LGKM0();
  const float pooled = pw[lane];

  // ---- BN + concat output ----
  float o0 = (pooled - mmean[lane]) * rsqrtf(mvar[lane] + 1e-3f) * gam[lane] + bet[lane];
  float o1 = (em_l - mmean[64 + lane]) * rsqrtf(mvar[64 + lane] + 1e-3f) * gam[64 + lane] + bet[64 + lane];
  float o2 = eu[(size_t)b * 64 + lane];
  float* ob = out + (size_t)b * 192;
  ob[lane]       = o0;
  ob[64 + lane]  = o1;
  ob[128 + lane] = o2;
}

extern "C" void kernel_launch(void* const* d_in, const int* in_sizes, int n_in,
                              void* d_out, int out_size, void* d_ws, size_t ws_size,
                              hipStream_t stream) {
  const float* em = (const float*)d_in[0];
  const float* eu = (const float*)d_in[1];
  const float* Xu = (const float*)d_in[2];
  const float* W1 = (const float*)d_in[3];
  const float* b1 = (const float*)d_in[4];
  const float* W2 = (const float*)d_in[5];
  const float* b2 = (const float*)d_in[6];
  const float* W3 = (const float*)d_in[7];
  const float* b3 = (const float*)d_in[8];
  const float* ga = (const float*)d_in[9];
  const float* be = (const float*)d_in[10];
  const float* mm = (const float*)d_in[11];
  const float* mv = (const float*)d_in[12];
  int B = in_sizes[0] / DD;

  float*  W1sT = (float*)d_ws;                          // 16 KB fp32
  bf16_t* Wbc  = (bf16_t*)((char*)d_ws + 64 * 64 * 4);  // 8 KB
  bf16_t* W1dt = Wbc + 64 * 64;                         // 8 KB
  bf16_t* W2t  = W1dt + 64 * 64;                        // 4 KB

  prep_kernel<<<1, 256, 0, stream>>>(W1, W2, Wbc, W1dt, W2t, W1sT);
  din_kernel<<<(B + 3) / 4, 256, 0, stream>>>(em, eu, Xu, b1, b2, W3, b3, ga, be,
                                              mm, mv, Wbc, W1dt, W2t, W1sT,
                                              (float*)d_out, B);
}

// Round 4
// 349.896 us; speedup vs baseline: 1.3207x; 1.3207x over previous
//
#include <hip/hip_runtime.h>
#include <hip/hip_bf16.h>
#include <math.h>

typedef __bf16 bf16_t;
typedef bf16_t bf16x2 __attribute__((ext_vector_type(2)));
typedef bf16_t bf16x8 __attribute__((ext_vector_type(8)));
typedef float  f32x4  __attribute__((ext_vector_type(4)));
typedef int    i32x4  __attribute__((ext_vector_type(4)));
typedef unsigned int u32;

#define SEQ 200
#define DD  64

#define MFMA(a, b, c) __builtin_amdgcn_mfma_f32_16x16x32_bf16((a), (b), (c), 0, 0, 0)

// ---------------- prep kernel (1 block): weight transforms only ----------------
__global__ __launch_bounds__(256) void prep_kernel(
    const float* __restrict__ W1, const float* __restrict__ W2,
    bf16_t* __restrict__ Wbc, bf16_t* __restrict__ W1dt,
    bf16_t* __restrict__ W2t, float* __restrict__ W1sT)
{
  const int tid = threadIdx.x;
  for (int i = tid; i < 64 * 64; i += 256) {
    int n = i >> 6, k = i & 63;
    Wbc[i]  = (bf16_t)(W1[(64 + k) * 64 + n] - W1[(128 + k) * 64 + n]);
    W1dt[i] = (bf16_t)(W1[(192 + k) * 64 + n]);
    W1sT[i] = W1[k * 64 + n] + W1[(128 + k) * 64 + n];   // fp32, exact Q
  }
  for (int i = tid; i < 32 * 64; i += 256) {
    int n = i >> 6, k = i & 63;
    W2t[i] = (bf16_t)(W2[k * 32 + n]);
  }
}

__device__ __forceinline__ u32 pk2(float x, float y) {
  bf16x2 t;
  t[0] = (bf16_t)fmaxf(x, 0.f);
  t[1] = (bf16_t)fmaxf(y, 0.f);
  return __builtin_bit_cast(u32, t);
}

#define XR4(v) { v += __shfl_xor(v, 1); v += __shfl_xor(v, 2); \
                 v += __shfl_xor(v, 4); v += __shfl_xor(v, 8); }
#define XM4(v) { v = fmaxf(v, __shfl_xor(v, 1)); v = fmaxf(v, __shfl_xor(v, 2)); \
                 v = fmaxf(v, __shfl_xor(v, 4)); v = fmaxf(v, __shfl_xor(v, 8)); }

// load one 16-row tile of Xu into named float4 regs (row clamped; invalid rows
// are masked later via softmax -inf, so their values only need to be finite)
#define LOADT(t, Y0, Y1, Y2, Y3) do {                                          \
    int row_ = 16 * (t) + l16;                                                 \
    row_ = row_ < SEQ ? row_ : (SEQ - 1);                                      \
    const float4* p_ = Xr + (row_ * 16 + 2 * g);                               \
    Y0 = p_[0]; Y1 = p_[1]; Y2 = p_[8]; Y3 = p_[9];                            \
  } while (0)

// fully-register per-tile pipeline (no LDS, no asm, no arrays):
// swapped stage-1 (H^T), shuffle-butterfly to stage-2 A-frags, stage-2/3,
// online softmax + pooling update.
#define PROC(MASKED, Y0, Y1, Y2, Y3) do {                                      \
    bf16x8 a0_, a1_;                                                           \
    a0_[0]=(bf16_t)Y0.x; a0_[1]=(bf16_t)Y0.y; a0_[2]=(bf16_t)Y0.z; a0_[3]=(bf16_t)Y0.w; \
    a0_[4]=(bf16_t)Y1.x; a0_[5]=(bf16_t)Y1.y; a0_[6]=(bf16_t)Y1.z; a0_[7]=(bf16_t)Y1.w; \
    a1_[0]=(bf16_t)Y2.x; a1_[1]=(bf16_t)Y2.y; a1_[2]=(bf16_t)Y2.z; a1_[3]=(bf16_t)Y2.w; \
    a1_[4]=(bf16_t)Y3.x; a1_[5]=(bf16_t)Y3.y; a1_[6]=(bf16_t)Y3.z; a1_[7]=(bf16_t)Y3.w; \
    f32x4 zz_ = {0.f, 0.f, 0.f, 0.f};                                          \
    f32x4 c0_ = MFMA(bB00, a0_, zz_); c0_ = MFMA(bB01, a1_, c0_);              \
    f32x4 c1_ = MFMA(bB10, a0_, zz_); c1_ = MFMA(bB11, a1_, c1_);              \
    f32x4 c2_ = MFMA(bB20, a0_, zz_); c2_ = MFMA(bB21, a1_, c2_);              \
    f32x4 c3_ = MFMA(bB30, a0_, zz_); c3_ = MFMA(bB31, a1_, c3_);              \
    u32 p00_ = pk2(c0_[0] + Q00, c0_[1] + Q01);                                \
    u32 p01_ = pk2(c0_[2] + Q02, c0_[3] + Q03);                                \
    u32 p10_ = pk2(c1_[0] + Q10, c1_[1] + Q11);                                \
    u32 p11_ = pk2(c1_[2] + Q12, c1_[3] + Q13);                                \
    u32 p20_ = pk2(c2_[0] + Q20, c2_[1] + Q21);                                \
    u32 p21_ = pk2(c2_[2] + Q22, c2_[3] + Q23);                                \
    u32 p30_ = pk2(c3_[0] + Q30, c3_[1] + Q31);                                \
    u32 p31_ = pk2(c3_[2] + Q32, c3_[3] + Q33);                                \
    u32 a00_ = __shfl(p00_, sl0), a01_ = __shfl(p01_, sl0);                    \
    u32 a10_ = __shfl(p10_, sl0), a11_ = __shfl(p11_, sl0);                    \
    u32 a20_ = __shfl(p20_, sl0), a21_ = __shfl(p21_, sl0);                    \
    u32 a30_ = __shfl(p30_, sl0), a31_ = __shfl(p31_, sl0);                    \
    u32 b00_ = __shfl(p00_, sl1), b01_ = __shfl(p01_, sl1);                    \
    u32 b10_ = __shfl(p10_, sl1), b11_ = __shfl(p11_, sl1);                    \
    u32 b20_ = __shfl(p20_, sl1), b21_ = __shfl(p21_, sl1);                    \
    u32 b30_ = __shfl(p30_, sl1), b31_ = __shfl(p31_, sl1);                    \
    i32x4 f0_ = { (int)(ghi ? a10_ : a00_), (int)(ghi ? a11_ : a01_),          \
                  (int)(ghi ? b10_ : b00_), (int)(ghi ? b11_ : b01_) };        \
    i32x4 f1_ = { (int)(ghi ? a30_ : a20_), (int)(ghi ? a31_ : a21_),          \
                  (int)(ghi ? b30_ : b20_), (int)(ghi ? b31_ : b21_) };        \
    bf16x8 hf0_ = __builtin_bit_cast(bf16x8, f0_);                             \
    bf16x8 hf1_ = __builtin_bit_cast(bf16x8, f1_);                             \
    f32x4 d0_ = MFMA(hf0_, W2f00, zz_); d0_ = MFMA(hf1_, W2f10, d0_);          \
    f32x4 d1_ = MFMA(hf0_, W2f01, zz_); d1_ = MFMA(hf1_, W2f11, d1_);          \
    float pr0_ = fmaxf(d0_[0] + b2v0, 0.f) * w3v0 + fmaxf(d1_[0] + b2v1, 0.f) * w3v1; \
    float pr1_ = fmaxf(d0_[1] + b2v0, 0.f) * w3v0 + fmaxf(d1_[1] + b2v1, 0.f) * w3v1; \
    float pr2_ = fmaxf(d0_[2] + b2v0, 0.f) * w3v0 + fmaxf(d1_[2] + b2v1, 0.f) * w3v1; \
    float pr3_ = fmaxf(d0_[3] + b2v0, 0.f) * w3v0 + fmaxf(d1_[3] + b2v1, 0.f) * w3v1; \
    XR4(pr0_) XR4(pr1_) XR4(pr2_) XR4(pr3_)                                    \
    float pv_ = pr0_;                                                          \
    pv_ = (s3 == 1) ? pr1_ : pv_;                                              \
    pv_ = (s3 == 2) ? pr2_ : pv_;                                              \
    pv_ = (s3 == 3) ? pr3_ : pv_;                                              \
    float lv_ = __shfl(pv_, lsrc) + b3s;                                       \
    if (MASKED && l16 >= 8) lv_ = -INFINITY;                                   \
    float tm_ = lv_;                                                           \
    XM4(tm_)                                                                   \
    float mn_ = fmaxf(m, tm_);                                                 \
    float al_ = __expf(m - mn_);                                               \
    float ee_ = __expf(lv_ - mn_);                                             \
    float S_ = ee_;                                                            \
    XR4(S_)                                                                    \
    Z = Z * al_ + S_;                                                          \
    Pa0 = Pa0 * al_ + ee_ * (float)a0_[0]; Pa1 = Pa1 * al_ + ee_ * (float)a0_[1]; \
    Pa2 = Pa2 * al_ + ee_ * (float)a0_[2]; Pa3 = Pa3 * al_ + ee_ * (float)a0_[3]; \
    Pa4 = Pa4 * al_ + ee_ * (float)a0_[4]; Pa5 = Pa5 * al_ + ee_ * (float)a0_[5]; \
    Pa6 = Pa6 * al_ + ee_ * (float)a0_[6]; Pa7 = Pa7 * al_ + ee_ * (float)a0_[7]; \
    Pb0 = Pb0 * al_ + ee_ * (float)a1_[0]; Pb1 = Pb1 * al_ + ee_ * (float)a1_[1]; \
    Pb2 = Pb2 * al_ + ee_ * (float)a1_[2]; Pb3 = Pb3 * al_ + ee_ * (float)a1_[3]; \
    Pb4 = Pb4 * al_ + ee_ * (float)a1_[4]; Pb5 = Pb5 * al_ + ee_ * (float)a1_[5]; \
    Pb6 = Pb6 * al_ + ee_ * (float)a1_[6]; Pb7 = Pb7 * al_ + ee_ * (float)a1_[7]; \
    m = mn_;                                                                   \
  } while (0)

// ---------------- main kernel: one wave per batch row; ZERO LDS, zero barriers ----
__global__ __launch_bounds__(256, 3) void din_kernel(
    const float* __restrict__ em, const float* __restrict__ eu,
    const float* __restrict__ Xu, const float* __restrict__ b1,
    const float* __restrict__ b2, const float* __restrict__ W3,
    const float* __restrict__ b3, const float* __restrict__ gam,
    const float* __restrict__ bet, const float* __restrict__ mmean,
    const float* __restrict__ mvar, const bf16_t* __restrict__ Wbc,
    const bf16_t* __restrict__ W1dt, const bf16_t* __restrict__ W2t,
    const float* __restrict__ W1sT, float* __restrict__ out, int Btot)
{
  const int tid  = threadIdx.x;
  const int lane = tid & 63;
  const int wid  = tid >> 6;
  const int g    = lane >> 4;
  const int l16  = lane & 15;
  const int b    = blockIdx.x * 4 + wid;
  if (b >= Btot) return;

  const int  sl0  = 32 * (g & 1) + l16;   // butterfly src lane (low half)
  const int  sl1  = sl0 + 16;             // butterfly src lane (high half)
  const bool ghi  = (g >> 1) != 0;
  const int  s3   = l16 & 3;
  const int  lsrc = ((l16 >> 2) << 4) | s3;

  const float* emr  = em + (size_t)b * DD;
  const float  em_l = emr[lane];
  float4 ef0 = *(const float4*)&emr[8 * g];
  float4 ef1 = *(const float4*)&emr[8 * g + 4];
  float4 ef2 = *(const float4*)&emr[32 + 8 * g];
  float4 ef3 = *(const float4*)&emr[32 + 8 * g + 4];

  // ---- stage-1 folded weight fragments (named, 8 regs of bf16x8) ----
  const bf16x8* Wbc8  = (const bf16x8*)Wbc;
  const bf16x8* W1dt8 = (const bf16x8*)W1dt;
  const bf16x8* W2t8  = (const bf16x8*)W2t;
#define MKBB(NAME, J, C, E0, E1)                                               \
  bf16x8 NAME; {                                                               \
    bf16x8 w_ = Wbc8[(16 * (J) + l16) * 8 + 4 * (C) + g];                      \
    bf16x8 d_ = W1dt8[(16 * (J) + l16) * 8 + 4 * (C) + g];                     \
    NAME[0] = (bf16_t)((float)w_[0] + E0.x * (float)d_[0]);                    \
    NAME[1] = (bf16_t)((float)w_[1] + E0.y * (float)d_[1]);                    \
    NAME[2] = (bf16_t)((float)w_[2] + E0.z * (float)d_[2]);                    \
    NAME[3] = (bf16_t)((float)w_[3] + E0.w * (float)d_[3]);                    \
    NAME[4] = (bf16_t)((float)w_[4] + E1.x * (float)d_[4]);                    \
    NAME[5] = (bf16_t)((float)w_[5] + E1.y * (float)d_[5]);                    \
    NAME[6] = (bf16_t)((float)w_[6] + E1.z * (float)d_[6]);                    \
    NAME[7] = (bf16_t)((float)w_[7] + E1.w * (float)d_[7]);                    \
  }
  MKBB(bB00, 0, 0, ef0, ef1) MKBB(bB01, 0, 1, ef2, ef3)
  MKBB(bB10, 1, 0, ef0, ef1) MKBB(bB11, 1, 1, ef2, ef3)
  MKBB(bB20, 2, 0, ef0, ef1) MKBB(bB21, 2, 1, ef2, ef3)
  MKBB(bB30, 3, 0, ef0, ef1) MKBB(bB31, 3, 1, ef2, ef3)
#undef MKBB

  const bf16x8 W2f00 = W2t8[(16 * 0 + l16) * 8 + 4 * 0 + g];
  const bf16x8 W2f01 = W2t8[(16 * 1 + l16) * 8 + 4 * 0 + g];
  const bf16x8 W2f10 = W2t8[(16 * 0 + l16) * 8 + 4 * 1 + g];
  const bf16x8 W2f11 = W2t8[(16 * 1 + l16) * 8 + 4 * 1 + g];

  const float b2v0 = b2[l16], b2v1 = b2[16 + l16];
  const float w3v0 = W3[l16], w3v1 = W3[16 + l16];
  const float b3s  = b3[0];

  // ---- Q[n=lane] in exact fp32, em broadcast via shuffles (no LDS) ----
  float q = b1[lane];
  {
    const float4* wq = (const float4*)(W1sT + lane * 64);
    #pragma unroll
    for (int dd = 0; dd < 16; ++dd) {
      float4 wv = wq[dd];
      float ex = __shfl(em_l, 4 * dd + 0);
      float ey = __shfl(em_l, 4 * dd + 1);
      float ez = __shfl(em_l, 4 * dd + 2);
      float ew = __shfl(em_l, 4 * dd + 3);
      q += ex * wv.x + ey * wv.y + ez * wv.z + ew * wv.w;
    }
  }
#define MKQ(NAME, J, R) const float NAME = __shfl(q, 16 * (J) + 4 * g + (R));
  MKQ(Q00, 0, 0) MKQ(Q01, 0, 1) MKQ(Q02, 0, 2) MKQ(Q03, 0, 3)
  MKQ(Q10, 1, 0) MKQ(Q11, 1, 1) MKQ(Q12, 1, 2) MKQ(Q13, 1, 3)
  MKQ(Q20, 2, 0) MKQ(Q21, 2, 1) MKQ(Q22, 2, 2) MKQ(Q23, 2, 3)
  MKQ(Q30, 3, 0) MKQ(Q31, 3, 1) MKQ(Q32, 3, 2) MKQ(Q33, 3, 3)
#undef MKQ

  // ---- online-softmax + pooling state (all named) ----
  float m = -INFINITY, Z = 0.f;
  float Pa0 = 0.f, Pa1 = 0.f, Pa2 = 0.f, Pa3 = 0.f;
  float Pa4 = 0.f, Pa5 = 0.f, Pa6 = 0.f, Pa7 = 0.f;
  float Pb0 = 0.f, Pb1 = 0.f, Pb2 = 0.f, Pb3 = 0.f;
  float Pb4 = 0.f, Pb5 = 0.f, Pb6 = 0.f, Pb7 = 0.f;

  const float4* Xr = (const float4*)(Xu + (size_t)b * SEQ * DD);

  // ---- 13-tile pipeline, depth-1 prefetch, rolled (2 tiles/iter) ----
  float4 A0, A1, A2, A3, B0, B1, B2, B3;
  LOADT(0, A0, A1, A2, A3);
  #pragma unroll 1
  for (int t = 0; t < 12; t += 2) {
    LOADT(t + 1, B0, B1, B2, B3);
    PROC(0, A0, A1, A2, A3);
    LOADT(t + 2, A0, A1, A2, A3);
    PROC(0, B0, B1, B2, B3);
  }
  PROC(1, A0, A1, A2, A3);   // tile 12: rows 192..207, mask l16>=8

  // ---- finalize pooling: reduce over the 16 s-classes ----
  XR4(Pa0) XR4(Pa1) XR4(Pa2) XR4(Pa3) XR4(Pa4) XR4(Pa5) XR4(Pa6) XR4(Pa7)
  XR4(Pb0) XR4(Pb1) XR4(Pb2) XR4(Pb3) XR4(Pb4) XR4(Pb5) XR4(Pb6) XR4(Pb7)
  const float invZ = 1.f / Z;

  // ---- lane L wants pooled[d=L]; gather via 16 shuffles + selects (no LDS) ----
  const int  gsrc = (lane >> 3) & 3;
  const int  srcl = 16 * gsrc + l16;
  const int  esel = lane & 7;
  const bool hi   = lane >= 32;
  float pooled = 0.f, t_;
  t_ = __shfl(Pa0, srcl); if (!hi && esel == 0) pooled = t_;
  t_ = __shfl(Pa1, srcl); if (!hi && esel == 1) pooled = t_;
  t_ = __shfl(Pa2, srcl); if (!hi && esel == 2) pooled = t_;
  t_ = __shfl(Pa3, srcl); if (!hi && esel == 3) pooled = t_;
  t_ = __shfl(Pa4, srcl); if (!hi && esel == 4) pooled = t_;
  t_ = __shfl(Pa5, srcl); if (!hi && esel == 5) pooled = t_;
  t_ = __shfl(Pa6, srcl); if (!hi && esel == 6) pooled = t_;
  t_ = __shfl(Pa7, srcl); if (!hi && esel == 7) pooled = t_;
  t_ = __shfl(Pb0, srcl); if (hi && esel == 0) pooled = t_;
  t_ = __shfl(Pb1, srcl); if (hi && esel == 1) pooled = t_;
  t_ = __shfl(Pb2, srcl); if (hi && esel == 2) pooled = t_;
  t_ = __shfl(Pb3, srcl); if (hi && esel == 3) pooled = t_;
  t_ = __shfl(Pb4, srcl); if (hi && esel == 4) pooled = t_;
  t_ = __shfl(Pb5, srcl); if (hi && esel == 5) pooled = t_;
  t_ = __shfl(Pb6, srcl); if (hi && esel == 6) pooled = t_;
  t_ = __shfl(Pb7, srcl); if (hi && esel == 7) pooled = t_;
  pooled *= invZ;

  // ---- BN + concat output ----
  float o0 = (pooled - mmean[lane]) * rsqrtf(mvar[lane] + 1e-3f) * gam[lane] + bet[lane];
  float o1 = (em_l - mmean[64 + lane]) * rsqrtf(mvar[64 + lane] + 1e-3f) * gam[64 + lane] + bet[64 + lane];
  float o2 = eu[(size_t)b * 64 + lane];
  float* ob = out + (size_t)b * 192;
  ob[lane]       = o0;
  ob[64 + lane]  = o1;
  ob[128 + lane] = o2;
}

extern "C" void kernel_launch(void* const* d_in, const int* in_sizes, int n_in,
                              void* d_out, int out_size, void* d_ws, size_t ws_size,
                              hipStream_t stream) {
  const float* em = (const float*)d_in[0];
  const float* eu = (const float*)d_in[1];
  const float* Xu = (const float*)d_in[2];
  const float* W1 = (const float*)d_in[3];
  const float* b1 = (const float*)d_in[4];
  const float* W2 = (const float*)d_in[5];
  const float* b2 = (const float*)d_in[6];
  const float* W3 = (const float*)d_in[7];
  const float* b3 = (const float*)d_in[8];
  const float* ga = (const float*)d_in[9];
  const float* be = (const float*)d_in[10];
  const float* mm = (const float*)d_in[11];
  const float* mv = (const float*)d_in[12];
  int B = in_sizes[0] / DD;

  float*  W1sT = (float*)d_ws;                          // 16 KB fp32
  bf16_t* Wbc  = (bf16_t*)((char*)d_ws + 64 * 64 * 4);  // 8 KB
  bf16_t* W1dt = Wbc + 64 * 64;                         // 8 KB
  bf16_t* W2t  = W1dt + 64 * 64;                        // 4 KB

  prep_kernel<<<1, 256, 0, stream>>>(W1, W2, Wbc, W1dt, W2t, W1sT);
  din_kernel<<<(B + 3) / 4, 256, 0, stream>>>(em, eu, Xu, b1, b2, W3, b3, ga, be,
                                              mm, mv, Wbc, W1dt, W2t, W1sT,
                                              (float*)d_out, B);
}

// Round 5
// 333.554 us; speedup vs baseline: 1.3854x; 1.0490x over previous
//
#include <hip/hip_runtime.h>
#include <hip/hip_bf16.h>
#include <math.h>

typedef __bf16 bf16_t;
typedef bf16_t bf16x2 __attribute__((ext_vector_type(2)));
typedef bf16_t bf16x8 __attribute__((ext_vector_type(8)));
typedef float  f32x4  __attribute__((ext_vector_type(4)));
typedef int    i32x4  __attribute__((ext_vector_type(4)));
typedef unsigned int u32;

#define SEQ 200
#define DD  64

#define MFMA(a, b, c) __builtin_amdgcn_mfma_f32_16x16x32_bf16((a), (b), (c), 0, 0, 0)

// ---------------- prep kernel (1 block): weight transforms ----------------
// Wbc/W1dt rows are PERMUTED so stage-1's packed MFMA output IS stage-2's
// B-fragment: storage row (16j + m) holds global n-column
//   nperm(j,m) = (j&1)*4 + (j>>1)*32 + 8*(m>>2) + (m&3)
__global__ __launch_bounds__(256) void prep_kernel(
    const float* __restrict__ W1, const float* __restrict__ W2,
    bf16_t* __restrict__ Wbc, bf16_t* __restrict__ W1dt,
    bf16_t* __restrict__ W2t, float* __restrict__ W1sT)
{
  const int tid = threadIdx.x;
  for (int i = tid; i < 64 * 64; i += 256) {
    int rp = i >> 6, k = i & 63;
    int j = rp >> 4, mm = rp & 15;
    int n = ((j & 1) << 2) | ((j >> 1) << 5) | ((mm >> 2) << 3) | (mm & 3);
    Wbc[i]  = (bf16_t)(W1[(64 + k) * 64 + n] - W1[(128 + k) * 64 + n]);
    W1dt[i] = (bf16_t)(W1[(192 + k) * 64 + n]);
    // W1sT unpermuted (Q gathered by global n): W1sT[n][d] = W1[d][n]+W1[128+d][n]
    W1sT[i] = W1[k * 64 + rp] + W1[(128 + k) * 64 + rp];
  }
  for (int i = tid; i < 32 * 64; i += 256) {
    int n = i >> 6, k = i & 63;
    W2t[i] = (bf16_t)(W2[k * 32 + n]);
  }
}

__device__ __forceinline__ u32 pk2(float x, float y) {
  bf16x2 t;
  t[0] = (bf16_t)fmaxf(x, 0.f);
  t[1] = (bf16_t)fmaxf(y, 0.f);
  return __builtin_bit_cast(u32, t);
}

#define XR4(v) { v += __shfl_xor(v, 1); v += __shfl_xor(v, 2); \
                 v += __shfl_xor(v, 4); v += __shfl_xor(v, 8); }
#define XM4(v) { v = fmaxf(v, __shfl_xor(v, 1)); v = fmaxf(v, __shfl_xor(v, 2)); \
                 v = fmaxf(v, __shfl_xor(v, 4)); v = fmaxf(v, __shfl_xor(v, 8)); }

// load one 16-row tile of Xu into named float4 regs (row clamped; invalid rows
// are masked via lv=-inf so their values only need to be finite)
#define LOADT(t, Y0, Y1, Y2, Y3) do {                                          \
    int row_ = 16 * (t) + l16;                                                 \
    row_ = row_ < SEQ ? row_ : (SEQ - 1);                                      \
    const float4* p_ = Xr + (row_ * 16 + 2 * g);                               \
    Y0 = p_[0]; Y1 = p_[1]; Y2 = p_[8]; Y3 = p_[9];                            \
  } while (0)

// per-tile pipeline, 2 cross-lane ops total:
// stage1 (swapped, perm-packed) -> stage2 (swapped) -> per-lane stage3 +
// 2-shfl reduce -> deferred-max online softmax + per-lane pooling
#define PROC(MASKED, Y0, Y1, Y2, Y3) do {                                      \
    bf16x8 a0_, a1_;                                                           \
    a0_[0]=(bf16_t)Y0.x; a0_[1]=(bf16_t)Y0.y; a0_[2]=(bf16_t)Y0.z; a0_[3]=(bf16_t)Y0.w; \
    a0_[4]=(bf16_t)Y1.x; a0_[5]=(bf16_t)Y1.y; a0_[6]=(bf16_t)Y1.z; a0_[7]=(bf16_t)Y1.w; \
    a1_[0]=(bf16_t)Y2.x; a1_[1]=(bf16_t)Y2.y; a1_[2]=(bf16_t)Y2.z; a1_[3]=(bf16_t)Y2.w; \
    a1_[4]=(bf16_t)Y3.x; a1_[5]=(bf16_t)Y3.y; a1_[6]=(bf16_t)Y3.z; a1_[7]=(bf16_t)Y3.w; \
    f32x4 zz_ = {0.f, 0.f, 0.f, 0.f};                                          \
    f32x4 c0_ = MFMA(bB00, a0_, zz_); c0_ = MFMA(bB01, a1_, c0_);              \
    f32x4 c1_ = MFMA(bB10, a0_, zz_); c1_ = MFMA(bB11, a1_, c1_);              \
    f32x4 c2_ = MFMA(bB20, a0_, zz_); c2_ = MFMA(bB21, a1_, c2_);              \
    f32x4 c3_ = MFMA(bB30, a0_, zz_); c3_ = MFMA(bB31, a1_, c3_);              \
    i32x4 f0_ = { (int)pk2(c0_[0] + Q00, c0_[1] + Q01),                        \
                  (int)pk2(c0_[2] + Q02, c0_[3] + Q03),                        \
                  (int)pk2(c1_[0] + Q10, c1_[1] + Q11),                        \
                  (int)pk2(c1_[2] + Q12, c1_[3] + Q13) };                      \
    i32x4 f1_ = { (int)pk2(c2_[0] + Q20, c2_[1] + Q21),                        \
                  (int)pk2(c2_[2] + Q22, c2_[3] + Q23),                        \
                  (int)pk2(c3_[0] + Q30, c3_[1] + Q31),                        \
                  (int)pk2(c3_[2] + Q32, c3_[3] + Q33) };                      \
    bf16x8 hf0_ = __builtin_bit_cast(bf16x8, f0_);                             \
    bf16x8 hf1_ = __builtin_bit_cast(bf16x8, f1_);                             \
    f32x4 d0_ = MFMA(W2fA0, hf0_, zz_); d0_ = MFMA(W2fA1, hf1_, d0_);          \
    f32x4 d1_ = MFMA(W2fB0, hf0_, zz_); d1_ = MFMA(W2fB1, hf1_, d1_);          \
    float pr_ = fmaxf(d0_[0] + b2lo.x, 0.f) * w3lo.x                           \
              + fmaxf(d0_[1] + b2lo.y, 0.f) * w3lo.y                           \
              + fmaxf(d0_[2] + b2lo.z, 0.f) * w3lo.z                           \
              + fmaxf(d0_[3] + b2lo.w, 0.f) * w3lo.w                           \
              + fmaxf(d1_[0] + b2hi.x, 0.f) * w3hi.x                           \
              + fmaxf(d1_[1] + b2hi.y, 0.f) * w3hi.y                           \
              + fmaxf(d1_[2] + b2hi.z, 0.f) * w3hi.z                           \
              + fmaxf(d1_[3] + b2hi.w, 0.f) * w3hi.w;                          \
    pr_ += __shfl_xor(pr_, 16);                                                \
    pr_ += __shfl_xor(pr_, 32);                                                \
    float lv_ = pr_ + b3s;                                                     \
    if (MASKED && l16 >= 8) lv_ = -INFINITY;                                   \
    if (!__all(lv_ <= m + 8.f)) {   /* wave-uniform rare path: max grew */     \
      float tm_ = lv_;                                                         \
      XM4(tm_)                                                                 \
      float mn_ = fmaxf(m, tm_);                                               \
      float al_ = __expf(m - mn_);                                             \
      Zp *= al_;                                                               \
      Pa0 *= al_; Pa1 *= al_; Pa2 *= al_; Pa3 *= al_;                          \
      Pa4 *= al_; Pa5 *= al_; Pa6 *= al_; Pa7 *= al_;                          \
      Pb0 *= al_; Pb1 *= al_; Pb2 *= al_; Pb3 *= al_;                          \
      Pb4 *= al_; Pb5 *= al_; Pb6 *= al_; Pb7 *= al_;                          \
      m = mn_;                                                                 \
    }                                                                          \
    float ee_ = __expf(lv_ - m);                                               \
    Zp += ee_;                                                                 \
    Pa0 += ee_ * (float)a0_[0]; Pa1 += ee_ * (float)a0_[1];                    \
    Pa2 += ee_ * (float)a0_[2]; Pa3 += ee_ * (float)a0_[3];                    \
    Pa4 += ee_ * (float)a0_[4]; Pa5 += ee_ * (float)a0_[5];                    \
    Pa6 += ee_ * (float)a0_[6]; Pa7 += ee_ * (float)a0_[7];                    \
    Pb0 += ee_ * (float)a1_[0]; Pb1 += ee_ * (float)a1_[1];                    \
    Pb2 += ee_ * (float)a1_[2]; Pb3 += ee_ * (float)a1_[3];                    \
    Pb4 += ee_ * (float)a1_[4]; Pb5 += ee_ * (float)a1_[5];                    \
    Pb6 += ee_ * (float)a1_[6]; Pb7 += ee_ * (float)a1_[7];                    \
  } while (0)

// ---------------- main kernel: one wave per batch row; zero LDS/barriers ----
__global__ __launch_bounds__(256, 3) void din_kernel(
    const float* __restrict__ em, const float* __restrict__ eu,
    const float* __restrict__ Xu, const float* __restrict__ b1,
    const float* __restrict__ b2, const float* __restrict__ W3,
    const float* __restrict__ b3, const float* __restrict__ gam,
    const float* __restrict__ bet, const float* __restrict__ mmean,
    const float* __restrict__ mvar, const bf16_t* __restrict__ Wbc,
    const bf16_t* __restrict__ W1dt, const bf16_t* __restrict__ W2t,
    const float* __restrict__ W1sT, float* __restrict__ out, int Btot)
{
  const int tid  = threadIdx.x;
  const int lane = tid & 63;
  const int wid  = tid >> 6;
  const int g    = lane >> 4;
  const int l16  = lane & 15;
  const int b    = blockIdx.x * 4 + wid;
  if (b >= Btot) return;

  const float* emr  = em + (size_t)b * DD;
  const float  em_l = emr[lane];
  float4 ef0 = *(const float4*)&emr[8 * g];
  float4 ef1 = *(const float4*)&emr[8 * g + 4];
  float4 ef2 = *(const float4*)&emr[32 + 8 * g];
  float4 ef3 = *(const float4*)&emr[32 + 8 * g + 4];

  // ---- stage-1 folded weight fragments (perm-packed rows) ----
  const bf16x8* Wbc8  = (const bf16x8*)Wbc;
  const bf16x8* W1dt8 = (const bf16x8*)W1dt;
  const bf16x8* W2t8  = (const bf16x8*)W2t;
#define MKBB(NAME, J, C, E0, E1)                                               \
  bf16x8 NAME; {                                                               \
    bf16x8 w_ = Wbc8[(16 * (J) + l16) * 8 + 4 * (C) + g];                      \
    bf16x8 d_ = W1dt8[(16 * (J) + l16) * 8 + 4 * (C) + g];                     \
    NAME[0] = (bf16_t)((float)w_[0] + E0.x * (float)d_[0]);                    \
    NAME[1] = (bf16_t)((float)w_[1] + E0.y * (float)d_[1]);                    \
    NAME[2] = (bf16_t)((float)w_[2] + E0.z * (float)d_[2]);                    \
    NAME[3] = (bf16_t)((float)w_[3] + E0.w * (float)d_[3]);                    \
    NAME[4] = (bf16_t)((float)w_[4] + E1.x * (float)d_[4]);                    \
    NAME[5] = (bf16_t)((float)w_[5] + E1.y * (float)d_[5]);                    \
    NAME[6] = (bf16_t)((float)w_[6] + E1.z * (float)d_[6]);                    \
    NAME[7] = (bf16_t)((float)w_[7] + E1.w * (float)d_[7]);                    \
  }
  MKBB(bB00, 0, 0, ef0, ef1) MKBB(bB01, 0, 1, ef2, ef3)
  MKBB(bB10, 1, 0, ef0, ef1) MKBB(bB11, 1, 1, ef2, ef3)
  MKBB(bB20, 2, 0, ef0, ef1) MKBB(bB21, 2, 1, ef2, ef3)
  MKBB(bB30, 3, 0, ef0, ef1) MKBB(bB31, 3, 1, ef2, ef3)
#undef MKBB

  // stage-2 A-operand (swapped): W2^T fragments. [c-half][n2-tile]
  const bf16x8 W2fA0 = W2t8[l16 * 8 + g];             // n2 0..15,  h 0..31
  const bf16x8 W2fA1 = W2t8[l16 * 8 + 4 + g];         // n2 0..15,  h 32..63
  const bf16x8 W2fB0 = W2t8[(16 + l16) * 8 + g];      // n2 16..31, h 0..31
  const bf16x8 W2fB1 = W2t8[(16 + l16) * 8 + 4 + g];  // n2 16..31, h 32..63

  // stage-3 constants indexed by this lane's n2 = 4g+r / 16+4g+r
  const float4 b2lo = *(const float4*)&b2[4 * g];
  const float4 b2hi = *(const float4*)&b2[16 + 4 * g];
  const float4 w3lo = *(const float4*)&W3[4 * g];
  const float4 w3hi = *(const float4*)&W3[16 + 4 * g];
  const float  b3s  = b3[0];

  // ---- Q[n=lane] in exact fp32, em broadcast via shuffles ----
  float q = b1[lane];
  {
    const float4* wq = (const float4*)(W1sT + lane * 64);
    #pragma unroll
    for (int dd = 0; dd < 16; ++dd) {
      float4 wv = wq[dd];
      float ex = __shfl(em_l, 4 * dd + 0);
      float ey = __shfl(em_l, 4 * dd + 1);
      float ez = __shfl(em_l, 4 * dd + 2);
      float ew = __shfl(em_l, 4 * dd + 3);
      q += ex * wv.x + ey * wv.y + ez * wv.z + ew * wv.w;
    }
  }
  // Q gathered with the SAME n-permutation as the weight rows
#define MKQ(NAME, J, R) const float NAME = __shfl(q, (((J)&1)<<2) + (((J)>>1)<<5) + 8*g + (R));
  MKQ(Q00, 0, 0) MKQ(Q01, 0, 1) MKQ(Q02, 0, 2) MKQ(Q03, 0, 3)
  MKQ(Q10, 1, 0) MKQ(Q11, 1, 1) MKQ(Q12, 1, 2) MKQ(Q13, 1, 3)
  MKQ(Q20, 2, 0) MKQ(Q21, 2, 1) MKQ(Q22, 2, 2) MKQ(Q23, 2, 3)
  MKQ(Q30, 3, 0) MKQ(Q31, 3, 1) MKQ(Q32, 3, 2) MKQ(Q33, 3, 3)
#undef MKQ

  // ---- deferred online-softmax + per-lane pooling state ----
  float m = -INFINITY, Zp = 0.f;
  float Pa0 = 0.f, Pa1 = 0.f, Pa2 = 0.f, Pa3 = 0.f;
  float Pa4 = 0.f, Pa5 = 0.f, Pa6 = 0.f, Pa7 = 0.f;
  float Pb0 = 0.f, Pb1 = 0.f, Pb2 = 0.f, Pb3 = 0.f;
  float Pb4 = 0.f, Pb5 = 0.f, Pb6 = 0.f, Pb7 = 0.f;

  const float4* Xr = (const float4*)(Xu + (size_t)b * SEQ * DD);

  // ---- 13-tile pipeline, depth-1 prefetch, named registers ----
  float4 A0, A1, A2, A3, B0, B1, B2, B3;
  LOADT(0, A0, A1, A2, A3);
  #pragma unroll 1
  for (int t = 0; t < 12; t += 2) {
    LOADT(t + 1, B0, B1, B2, B3);
    PROC(0, A0, A1, A2, A3);
    LOADT(t + 2, A0, A1, A2, A3);
    PROC(0, B0, B1, B2, B3);
  }
  PROC(1, A0, A1, A2, A3);   // tile 12: rows 192..207, mask l16>=8

  // ---- finalize: Z across the 16 s-classes, then pooled reduction ----
  float Z = Zp;
  XR4(Z)
  const float invZ = 1.f / Z;
  XR4(Pa0) XR4(Pa1) XR4(Pa2) XR4(Pa3) XR4(Pa4) XR4(Pa5) XR4(Pa6) XR4(Pa7)
  XR4(Pb0) XR4(Pb1) XR4(Pb2) XR4(Pb3) XR4(Pb4) XR4(Pb5) XR4(Pb6) XR4(Pb7)

  // ---- lane L wants pooled[d=L]; gather via 16 shuffles + selects ----
  const int  gsrc = (lane >> 3) & 3;
  const int  srcl = 16 * gsrc + l16;
  const int  esel = lane & 7;
  const bool hi   = lane >= 32;
  float pooled = 0.f, t_;
  t_ = __shfl(Pa0, srcl); if (!hi && esel == 0) pooled = t_;
  t_ = __shfl(Pa1, srcl); if (!hi && esel == 1) pooled = t_;
  t_ = __shfl(Pa2, srcl); if (!hi && esel == 2) pooled = t_;
  t_ = __shfl(Pa3, srcl); if (!hi && esel == 3) pooled = t_;
  t_ = __shfl(Pa4, srcl); if (!hi && esel == 4) pooled = t_;
  t_ = __shfl(Pa5, srcl); if (!hi && esel == 5) pooled = t_;
  t_ = __shfl(Pa6, srcl); if (!hi && esel == 6) pooled = t_;
  t_ = __shfl(Pa7, srcl); if (!hi && esel == 7) pooled = t_;
  t_ = __shfl(Pb0, srcl); if (hi && esel == 0) pooled = t_;
  t_ = __shfl(Pb1, srcl); if (hi && esel == 1) pooled = t_;
  t_ = __shfl(Pb2, srcl); if (hi && esel == 2) pooled = t_;
  t_ = __shfl(Pb3, srcl); if (hi && esel == 3) pooled = t_;
  t_ = __shfl(Pb4, srcl); if (hi && esel == 4) pooled = t_;
  t_ = __shfl(Pb5, srcl); if (hi && esel == 5) pooled = t_;
  t_ = __shfl(Pb6, srcl); if (hi && esel == 6) pooled = t_;
  t_ = __shfl(Pb7, srcl); if (hi && esel == 7) pooled = t_;
  pooled *= invZ;

  // ---- BN + concat output ----
  float o0 = (pooled - mmean[lane]) * rsqrtf(mvar[lane] + 1e-3f) * gam[lane] + bet[lane];
  float o1 = (em_l - mmean[64 + lane]) * rsqrtf(mvar[64 + lane] + 1e-3f) * gam[64 + lane] + bet[64 + lane];
  float o2 = eu[(size_t)b * 64 + lane];
  float* ob = out + (size_t)b * 192;
  ob[lane]       = o0;
  ob[64 + lane]  = o1;
  ob[128 + lane] = o2;
}

extern "C" void kernel_launch(void* const* d_in, const int* in_sizes, int n_in,
                              void* d_out, int out_size, void* d_ws, size_t ws_size,
                              hipStream_t stream) {
  const float* em = (const float*)d_in[0];
  const float* eu = (const float*)d_in[1];
  const float* Xu = (const float*)d_in[2];
  const float* W1 = (const float*)d_in[3];
  const float* b1 = (const float*)d_in[4];
  const float* W2 = (const float*)d_in[5];
  const float* b2 = (const float*)d_in[6];
  const float* W3 = (const float*)d_in[7];
  const float* b3 = (const float*)d_in[8];
  const float* ga = (const float*)d_in[9];
  const float* be = (const float*)d_in[10];
  const float* mm = (const float*)d_in[11];
  const float* mv = (const float*)d_in[12];
  int B = in_sizes[0] / DD;

  float*  W1sT = (float*)d_ws;                          // 16 KB fp32
  bf16_t* Wbc  = (bf16_t*)((char*)d_ws + 64 * 64 * 4);  // 8 KB
  bf16_t* W1dt = Wbc + 64 * 64;                         // 8 KB
  bf16_t* W2t  = W1dt + 64 * 64;                        // 4 KB

  prep_kernel<<<1, 256, 0, stream>>>(W1, W2, Wbc, W1dt, W2t, W1sT);
  din_kernel<<<(B + 3) / 4, 256, 0, stream>>>(em, eu, Xu, b1, b2, W3, b3, ga, be,
                                              mm, mv, Wbc, W1dt, W2t, W1sT,
                                              (float*)d_out, B);
}